// Round 4
// baseline (275.263 us; speedup 1.0000x reference)
//
#include <hip/hip_runtime.h>
#include <math.h>

#define N_NODES 100000
#define N_EDGES 1600000
#define EPS_    1e-5f

// R12: eliminate the 1.6M per-edge global atomics (R8-R11: duration pinned at
// 125-129us across every traffic/ALU/layout variation; only invariant = atomic
// count; ~24cy/atomic/channel service rate). Counting-sort into 782 dst-buckets
// (128 nodes each) via LDS histograms; global atomics shrink to 98x782=76K
// block-bucket base reservations. ELL lives only in LDS inside the gather
// kernel; hb_g stays unscaled and dinv[src] is folded per edge (matches the
// reference sum hg[src]*dinv[src]*dinv[dst] exactly).

#define NBKT     782        // ceil(N/128)
#define BKT_CAP  3072       // mean 2048, +22 sigma -- unreachable
#define PAD_L    64         // per-node ELL capacity (P(Poisson(16)>=64)~1e-20)

#define NB_LIN   391        // 391 blocks * 4 waves = 1564 >= 1563 chunks
#define LIN_CHUNKS 1563

#define NB_BIN   98
#define EPB      16384      // 98*16384 = 1,605,632 >= E

// ---- bf16 helpers (raw ushort storage, RNE on pack) -----------------------
__device__ __forceinline__ float bf2f(unsigned short u) {
    union { unsigned int i; float f; } v; v.i = (unsigned int)u << 16; return v.f;
}
__device__ __forceinline__ unsigned short f2bf(float f) {
    union { float f; unsigned int i; } v; v.f = f;
    unsigned int b = v.i + 0x7FFFu + ((v.i >> 16) & 1u);   // round-to-nearest-even
    return (unsigned short)(b >> 16);
}

// ---------------------------------------------------------------------------
// Kernel 1: bin_scatter. Per block: LDS histogram of 16K edges over 782
// buckets -> one global atomicAdd per nonempty bucket (base reservation) ->
// LDS-rank scatter of packed (src<<7 | dst&127) into the bucket segment.
// ---------------------------------------------------------------------------
__global__ void bin_scatter_kernel(const int* __restrict__ src,
                                   const int* __restrict__ dst,
                                   int* __restrict__ bktCnt,
                                   int* __restrict__ bkt)
{
    __shared__ int hist[NBKT];
    __shared__ int hbase[NBKT];
    const int tl = threadIdx.x;
    const int e0 = blockIdx.x * EPB;
    const int ne = min(EPB, N_EDGES - e0);

    for (int i = tl; i < NBKT; i += 256) hist[i] = 0;
    __syncthreads();

    for (int i = tl; i < ne; i += 256)
        atomicAdd(&hist[dst[e0 + i] >> 7], 1);
    __syncthreads();

    for (int i = tl; i < NBKT; i += 256) {
        const int h = hist[i];
        hbase[i] = h ? atomicAdd(&bktCnt[i], h) : 0;
        hist[i]  = 0;                         // reuse as rank counter
    }
    __syncthreads();

    for (int i = tl; i < ne; i += 256) {
        const int d = dst[e0 + i];
        const int s = src[e0 + i];
        const int b = d >> 7;
        const int r = hbase[b] + atomicAdd(&hist[b], 1);
        if (r < BKT_CAP)
            bkt[(size_t)b * BKT_CAP + r] = (s << 7) | (d & 127);
    }
}

// ---------------------------------------------------------------------------
// Kernel 2: lin (R10 form). lane = node; weights via wave-uniform scalar
// broadcasts; acc[64] in VGPRs. hb_g stored UNSCALED (dinv folded in gather).
// ---------------------------------------------------------------------------
__global__ void lin_kernel(const float* __restrict__ x,
                           const float* __restrict__ W1,
                           const float* __restrict__ b1,
                           const float* __restrict__ Wg,
                           unsigned short* __restrict__ hb_g)
{
    const int tl    = threadIdx.x;
    const int chunk = blockIdx.x * 4 + (tl >> 6);
    if (chunk >= LIN_CHUNKS) return;

    const int lane = tl & 63;
    const int n    = chunk * 64 + lane;
    const bool act = (n < N_NODES);
    float x0 = 0.f, x1 = 0.f, x2 = 0.f;
    if (act) { x0 = x[n * 3]; x1 = x[n * 3 + 1]; x2 = x[n * 3 + 2]; }

    float acc[64];
#pragma unroll
    for (int c = 0; c < 64; ++c) acc[c] = 0.f;

#pragma unroll 2
    for (int k = 0; k < 64; ++k) {
        const float w0 = W1[k];               // wave-uniform -> s_load
        const float w1 = W1[64 + k];
        const float w2 = W1[128 + k];
        const float bb = b1[k];
        float hk = fmaf(x0, w0, fmaf(x1, w1, fmaf(x2, w2, bb)));
        hk = fmaxf(hk, 0.f);
        const float* __restrict__ wr = Wg + k * 64;    // uniform row
#pragma unroll
        for (int c = 0; c < 64; ++c) acc[c] = fmaf(hk, wr[c], acc[c]);
    }

    if (act) {
        unsigned int o[32];
#pragma unroll
        for (int c = 0; c < 32; ++c)
            o[c] = (unsigned int)f2bf(acc[2 * c])
                 | ((unsigned int)f2bf(acc[2 * c + 1]) << 16);
        uint4* __restrict__ dp = (uint4*)(hb_g + (size_t)n * 64);
#pragma unroll
        for (int q = 0; q < 8; ++q)
            dp[q] = make_uint4(o[4 * q], o[4 * q + 1], o[4 * q + 2], o[4 * q + 3]);
    }
}

// ---------------------------------------------------------------------------
// Kernel 3: per-bucket degree count -> dinv[n] = rsqrt(deg+1)
// ---------------------------------------------------------------------------
__global__ void dinv_kernel(const int* __restrict__ bktCnt,
                            const int* __restrict__ bkt,
                            float* __restrict__ dinv)
{
    __shared__ int lcnt[128];
    const int tl = threadIdx.x;
    const int b  = blockIdx.x;
    if (tl < 128) lcnt[tl] = 0;
    __syncthreads();

    const int ne = min(bktCnt[b], BKT_CAP);
    const int* __restrict__ bb = bkt + (size_t)b * BKT_CAP;
    for (int i = tl; i < ne; i += 256) atomicAdd(&lcnt[bb[i] & 127], 1);
    __syncthreads();

    if (tl < 128) {
        const int n = b * 128 + tl;
        if (n < N_NODES) dinv[n] = rsqrtf((float)(lcnt[tl] + 1));
    }
}

// ---------------------------------------------------------------------------
// Kernel 4: gather + epilogue. One block per bucket: rebuild per-node edge
// lists in LDS (32KB), then wave-per-node gather with dinv[src] folded.
//   acc = dinv[n]*hg[n] + sum_j dinv[src_j]*hg[src_j]
//   h2  = relu(dinv[n]*acc + bg);  h = relu(x.W1+b1)
//   out = LayerNorm128([h,h2])*gamma + beta
// ---------------------------------------------------------------------------
__global__ void gather_final_kernel(const unsigned short* __restrict__ hb_g,
                                    const int* __restrict__ bktCnt,
                                    const int* __restrict__ bkt,
                                    const float* __restrict__ dinv,
                                    const float* __restrict__ x,
                                    const float* __restrict__ W1,
                                    const float* __restrict__ b1,
                                    const float* __restrict__ bg,
                                    const float* __restrict__ gamma,
                                    const float* __restrict__ beta,
                                    float* __restrict__ out)
{
    __shared__ int sell[128 * PAD_L];     // 32 KB
    __shared__ int lcnt[128];
    const int tl = threadIdx.x;           // 512 threads = 8 waves
    const int b  = blockIdx.x;

    if (tl < 128) lcnt[tl] = 0;
    __syncthreads();

    const int ne = min(bktCnt[b], BKT_CAP);
    const int* __restrict__ bb = bkt + (size_t)b * BKT_CAP;
    for (int i = tl; i < ne; i += 512) {
        const int v  = bb[i];
        const int dl = v & 127;
        const int r  = atomicAdd(&lcnt[dl], 1);
        if (r < PAD_L) sell[dl * PAD_L + r] = v >> 7;
    }
    __syncthreads();

    const int lane = tl & 63;
    const int w    = tl >> 6;
    // per-lane invariants hoisted out of the node loop
    const float w0 = W1[lane], w1 = W1[64 + lane], w2 = W1[128 + lane];
    const float bb1 = b1[lane];
    const float bgl = bg[lane];
    const float g0 = gamma[lane], g1 = gamma[64 + lane];
    const float be0 = beta[lane], be1 = beta[64 + lane];

    for (int nl = w; nl < 128; nl += 8) {
        const int n = b * 128 + nl;
        if (n >= N_NODES) break;          // only bucket 781's tail

        const int c    = lcnt[nl];
        const float di = rsqrtf((float)(c + 1));
        const int deg  = (c < PAD_L) ? c : PAD_L;
        const int* row = sell + nl * PAD_L;

        const float xx0 = x[n * 3], xx1 = x[n * 3 + 1], xx2 = x[n * 3 + 2];
        float acc = di * bf2f(hb_g[(size_t)n * 64 + lane]);   // self loop

        int j = 0;
        for (; j + 8 <= deg; j += 8) {                        // 8 gathers in flight
            const int s0 = row[j + 0], s1 = row[j + 1], s2 = row[j + 2], s3 = row[j + 3];
            const int s4 = row[j + 4], s5 = row[j + 5], s6 = row[j + 6], s7 = row[j + 7];
            const float a0 = bf2f(hb_g[(size_t)s0 * 64 + lane]);
            const float a1 = bf2f(hb_g[(size_t)s1 * 64 + lane]);
            const float a2 = bf2f(hb_g[(size_t)s2 * 64 + lane]);
            const float a3 = bf2f(hb_g[(size_t)s3 * 64 + lane]);
            const float a4 = bf2f(hb_g[(size_t)s4 * 64 + lane]);
            const float a5 = bf2f(hb_g[(size_t)s5 * 64 + lane]);
            const float a6 = bf2f(hb_g[(size_t)s6 * 64 + lane]);
            const float a7 = bf2f(hb_g[(size_t)s7 * 64 + lane]);
            const float v0 = dinv[s0], v1 = dinv[s1], v2 = dinv[s2], v3 = dinv[s3];
            const float v4 = dinv[s4], v5 = dinv[s5], v6 = dinv[s6], v7 = dinv[s7];
            acc = fmaf(v0, a0, acc); acc = fmaf(v1, a1, acc);
            acc = fmaf(v2, a2, acc); acc = fmaf(v3, a3, acc);
            acc = fmaf(v4, a4, acc); acc = fmaf(v5, a5, acc);
            acc = fmaf(v6, a6, acc); acc = fmaf(v7, a7, acc);
        }
        for (; j < deg; ++j) {
            const int s = row[j];
            acc = fmaf(dinv[s], bf2f(hb_g[(size_t)s * 64 + lane]), acc);
        }

        float h  = fmaxf(fmaf(xx0, w0, fmaf(xx1, w1, fmaf(xx2, w2, bb1))), 0.f);
        float h2 = fmaxf(fmaf(di, acc, bgl), 0.f);

        float sum = h + h2;
#pragma unroll
        for (int o = 32; o > 0; o >>= 1) sum += __shfl_xor(sum, o, 64);
        const float mu = sum * (1.0f / 128.0f);

        const float dA = h  - mu;
        const float dB = h2 - mu;
        float vs = dA * dA + dB * dB;
#pragma unroll
        for (int o = 32; o > 0; o >>= 1) vs += __shfl_xor(vs, o, 64);
        const float rr = rsqrtf(vs * (1.0f / 128.0f) + EPS_);

        out[(size_t)n * 128 + lane]      = dA * rr * g0 + be0;
        out[(size_t)n * 128 + 64 + lane] = dB * rr * g1 + be1;
    }
}

// ---------------------------------------------------------------------------
extern "C" void kernel_launch(void* const* d_in, const int* in_sizes, int n_in,
                              void* d_out, int out_size, void* d_ws, size_t ws_size,
                              hipStream_t stream)
{
    const float* x     = (const float*)d_in[0];
    const int*   edge  = (const int*)  d_in[1];   // [2, E]: row0 = src, row1 = dst
    const float* W1    = (const float*)d_in[2];
    const float* b1    = (const float*)d_in[3];
    const float* Wg    = (const float*)d_in[4];
    const float* bg    = (const float*)d_in[5];
    const float* gamma = (const float*)d_in[6];
    const float* beta  = (const float*)d_in[7];
    float*       out   = (float*)d_out;

    // Workspace (~23 MB): hb_g | bkt | bktCnt | dinv
    char*  ws  = (char*)d_ws;
    size_t p   = 0;
    unsigned short* hb_g = (unsigned short*)(ws + p); p += (size_t)N_NODES * 64 * sizeof(unsigned short);
    int*            bkt  = (int*)           (ws + p); p += (size_t)NBKT * BKT_CAP * sizeof(int);
    int*          bktCnt = (int*)           (ws + p); p += (size_t)NBKT * sizeof(int);
    float*          dinv = (float*)         (ws + p);

    const int* src = edge;
    const int* dst = edge + N_EDGES;

    hipMemsetAsync(bktCnt, 0, (size_t)NBKT * sizeof(int), stream);

    bin_scatter_kernel<<<NB_BIN, 256, 0, stream>>>(src, dst, bktCnt, bkt);
    lin_kernel<<<NB_LIN, 256, 0, stream>>>(x, W1, b1, Wg, hb_g);
    dinv_kernel<<<NBKT, 256, 0, stream>>>(bktCnt, bkt, dinv);
    gather_final_kernel<<<NBKT, 512, 0, stream>>>(hb_g, bktCnt, bkt, dinv,
                                                  x, W1, b1, bg, gamma, beta, out);
}